// Round 13
// baseline (233.558 us; speedup 1.0000x reference)
//
#include <hip/hip_runtime.h>

#define D 128
#define BN_EPS 1e-5f
#define GEMM_GRID 512
#define GEMM_TILE 32
#define AGG_BLOCKS 2048
#define MFMA_GRID 512
#define TILE_SHIFT 14          // 16384 hb rows/tile = 4MB = one XCD L2
#define EB_CAP 2048

typedef __attribute__((ext_vector_type(8))) short short8v;   // 8 bf16 (4 VGPR)
typedef __attribute__((ext_vector_type(4))) float float4v;   // MFMA C/D

__device__ __forceinline__ unsigned int f2bf(float f) {      // f32 -> bf16 RNE
  unsigned int bits = __float_as_uint(f);
  return (bits + 0x7fffu + ((bits >> 16) & 1u)) >> 16;
}

__device__ __forceinline__ void add8(float* acc, uint4 v) {  // acc += bf16x8
  acc[0] += __uint_as_float(v.x << 16);
  acc[1] += __uint_as_float(v.x & 0xffff0000u);
  acc[2] += __uint_as_float(v.y << 16);
  acc[3] += __uint_as_float(v.y & 0xffff0000u);
  acc[4] += __uint_as_float(v.z << 16);
  acc[5] += __uint_as_float(v.z & 0xffff0000u);
  acc[6] += __uint_as_float(v.w << 16);
  acc[7] += __uint_as_float(v.w & 0xffff0000u);
}

// ==================== CSR build (ordered 3-kernel scan) ====================
__global__ __launch_bounds__(256) void degree_i_kernel(
    const int* __restrict__ col, int* __restrict__ cnt, int E) {
  int e = blockIdx.x * 256 + threadIdx.x;
  if (e < E) atomicAdd(&cnt[col[e]], 1);
}

__global__ __launch_bounds__(256) void scanA_kernel(
    const int* __restrict__ cnt, float* __restrict__ dis,
    int* __restrict__ partials, int N) {
  __shared__ int l[256];
  int t = threadIdx.x;
  int i = blockIdx.x * 256 + t;
  int v = (i < N) ? cnt[i] : 0;
  if (i < N) dis[i] = (v > 0) ? rsqrtf((float)v) : 0.0f;
  l[t] = v; __syncthreads();
  for (int s = 128; s > 0; s >>= 1) {
    if (t < s) l[t] += l[t + s];
    __syncthreads();
  }
  if (t == 0) partials[blockIdx.x] = l[0];
}

__global__ void scanB_kernel(int* __restrict__ partials, int nb) {
  __shared__ int l[512];
  int t = threadIdx.x;
  l[t] = (t < nb) ? partials[t] : 0;
  __syncthreads();
  for (int off = 1; off < 512; off <<= 1) {
    int v = (t >= off) ? l[t - off] : 0;
    __syncthreads();
    l[t] += v;
    __syncthreads();
  }
  if (t < nb) partials[t] = (t == 0) ? 0 : l[t - 1];
}

__global__ __launch_bounds__(256) void scanC_kernel(
    const int* __restrict__ cnt, const int* __restrict__ partials,
    int* __restrict__ offsets, int N) {
  __shared__ int l[256];
  int t = threadIdx.x;
  int i = blockIdx.x * 256 + t;
  int v = (i < N) ? cnt[i] : 0;
  l[t] = v; __syncthreads();
  for (int off = 1; off < 256; off <<= 1) {
    int u = (t >= off) ? l[t - off] : 0;
    __syncthreads();
    l[t] += u;
    __syncthreads();
  }
  if (i < N) offsets[i] = partials[blockIdx.x] + l[t] - v;
}

__global__ __launch_bounds__(256) void bucket_kernel(
    const int* __restrict__ ei, const int* __restrict__ offsets,
    int* __restrict__ cursor, int* __restrict__ csr_row, int E) {
  int e = blockIdx.x * 256 + threadIdx.x;
  if (e < E) {
    int c = ei[E + e];
    int p = offsets[c] + atomicAdd(&cursor[c], 1);
    csr_row[p] = ei[e];
  }
}

// ==================== W -> Wt bf16 (transposed) ============================
__global__ __launch_bounds__(256) void cvt_w_kernel(
    const float* __restrict__ W, unsigned short* __restrict__ Wt) {
  int idx = blockIdx.x * 256 + threadIdx.x;   // grid 64 -> 16384
  int k = idx >> 7, n = idx & 127;
  Wt[n * D + k] = (unsigned short)f2bf(W[idx]);
}

// ====== h' = dis .* (x @ W) via bf16 MFMA, written bf16, grid-stride =======
__global__ __launch_bounds__(256) void gemm_mfma_kernel(
    const float* __restrict__ x, const unsigned short* __restrict__ Wt,
    const float* __restrict__ dis, unsigned short* __restrict__ hb, int N) {
  __shared__ unsigned short Wl[D * D];        // 32 KB
  int t = threadIdx.x;
  {
    const uint4* src = (const uint4*)Wt;
    uint4* dst = (uint4*)Wl;
#pragma unroll
    for (int i = 0; i < 8; ++i) {
      int idx = t + i * 256;                  // uint4 index; row n = idx>>4
      dst[idx ^ ((idx >> 4) & 7)] = src[idx];
    }
  }
  __syncthreads();
  int wave = t >> 6, lane = t & 63;
  int r16 = lane & 15, kg = lane >> 4;        // A-row / k-group within frag
  const float4* x4 = (const float4*)x;

  for (int bb = blockIdx.x * 64; bb < N; bb += MFMA_GRID * 64) {
    int tilebase = bb + wave * 16;
    int arow = tilebase + r16;
    bool rowok = arow < N;

    short8v afrag[4];
#pragma unroll
    for (int kc = 0; kc < 4; ++kc) {
      float4 lo = make_float4(0.f, 0.f, 0.f, 0.f);
      float4 hi = make_float4(0.f, 0.f, 0.f, 0.f);
      if (rowok) {
        lo = x4[(size_t)arow * 32 + kc * 8 + kg * 2];
        hi = x4[(size_t)arow * 32 + kc * 8 + kg * 2 + 1];
      }
      short8v a;
      a[0] = (short)f2bf(lo.x); a[1] = (short)f2bf(lo.y);
      a[2] = (short)f2bf(lo.z); a[3] = (short)f2bf(lo.w);
      a[4] = (short)f2bf(hi.x); a[5] = (short)f2bf(hi.y);
      a[6] = (short)f2bf(hi.z); a[7] = (short)f2bf(hi.w);
      afrag[kc] = a;
    }

    float dv[4];
#pragma unroll
    for (int reg = 0; reg < 4; ++reg) {
      int r = tilebase + kg * 4 + reg;
      dv[reg] = (r < N) ? dis[r] : 0.f;
    }

#pragma unroll
    for (int ct = 0; ct < 8; ++ct) {          // 8 col-tiles of 16
      float4v c = {0.f, 0.f, 0.f, 0.f};
      int n = ct * 16 + r16;                  // B col this lane loads
#pragma unroll
      for (int kc = 0; kc < 4; ++kc) {
        int u = (n * D + kc * 32 + kg * 8) ^ ((n & 7) << 3);
        short8v b = *(const short8v*)&Wl[u];
        c = __builtin_amdgcn_mfma_f32_16x16x32_bf16(afrag[kc], b, c, 0, 0, 0);
      }
      // C/D layout (m89-verified): col = lane&15, row = (lane>>4)*4 + reg
#pragma unroll
      for (int reg = 0; reg < 4; ++reg) {
        int r = tilebase + kg * 4 + reg;
        if (r < N)
          hb[(size_t)r * D + ct * 16 + r16] = (unsigned short)f2bf(c[reg] * dv[reg]);
      }
    }
  }
}

// === aggregation: L2-TILED bf16 gather + fused BN stats, quarter-per-node ==
// Block caches its 16 nodes' contiguous csr segment in LDS, then sweeps
// source-tiles of 2^TILE_SHIFT rows (4MB of hb = one XCD L2).  All blocks
// sweep tiles in the same order, so gathers concentrate on an L2-resident
// slice.  acc persists in registers across tiles.
__global__ __launch_bounds__(256) void csr_agg_tiled_kernel(
    const int* __restrict__ csr_row, const int* __restrict__ offsets,
    const float* __restrict__ dis, const uint4* __restrict__ hb,
    uint4* __restrict__ agb, float* __restrict__ sums, int N, int E,
    int ntiles) {
  __shared__ int eb[EB_CAP];     // 8 KB edge cache
  __shared__ float red[16][D];   // 8 KB stats reduction
  int t   = threadIdx.x;
  int l16 = t & 15;
  int g   = t >> 4;
  float sA[8] = {}, sQ[8] = {};

  for (int c0 = blockIdx.x * 16; c0 < N; c0 += gridDim.x * 16) {
    int gend = c0 + 16;
    int s0 = offsets[c0];
    int e0 = (gend < N) ? offsets[gend] : E;
    int total = e0 - s0;
    int c = c0 + g;
    int s = 0, e = 0;
    if (c < N) {
      s = offsets[c] - s0;
      e = ((c + 1 < N) ? offsets[c + 1] : E) - s0;
    }
    float acc[8] = {};

    if (total <= EB_CAP) {               // block-uniform branch
      __syncthreads();                   // eb free from previous iteration
      for (int i = t; i < total; i += 256) eb[i] = csr_row[s0 + i];
      __syncthreads();
      for (int tile = 0; tile < ntiles; ++tile) {
        int lo = tile << TILE_SHIFT;
        int hi = lo + (1 << TILE_SHIFT);
        for (int i = s; i < e; ++i) {
          int r = eb[i];
          if (r >= lo && r < hi) {
            uint4 v = hb[(size_t)r * 16 + l16];
            add8(acc, v);
          }
        }
      }
    } else {                             // rare: huge group, direct path
      for (int i = s; i < e; ++i) {
        int r = csr_row[s0 + i];
        uint4 v = hb[(size_t)r * 16 + l16];
        add8(acc, v);
      }
    }

    if (c < N) {
      float wc = dis[c];
      float v0 = acc[0]*wc, v1 = acc[1]*wc, v2 = acc[2]*wc, v3 = acc[3]*wc;
      float v4 = acc[4]*wc, v5 = acc[5]*wc, v6 = acc[6]*wc, v7 = acc[7]*wc;
      uint4 o;
      o.x = f2bf(v0) | (f2bf(v1) << 16);
      o.y = f2bf(v2) | (f2bf(v3) << 16);
      o.z = f2bf(v4) | (f2bf(v5) << 16);
      o.w = f2bf(v6) | (f2bf(v7) << 16);
      agb[(size_t)c * 16 + l16] = o;
      sA[0]+=v0; sA[1]+=v1; sA[2]+=v2; sA[3]+=v3;
      sA[4]+=v4; sA[5]+=v5; sA[6]+=v6; sA[7]+=v7;
      sQ[0]+=v0*v0; sQ[1]+=v1*v1; sQ[2]+=v2*v2; sQ[3]+=v3*v3;
      sQ[4]+=v4*v4; sQ[5]+=v5*v5; sQ[6]+=v6*v6; sQ[7]+=v7*v7;
    }
  }

  __syncthreads();
#pragma unroll
  for (int j = 0; j < 8; ++j) red[g][l16 * 8 + j] = sA[j];
  __syncthreads();
  if (t < D) {
    float v = 0.f;
#pragma unroll
    for (int r = 0; r < 16; ++r) v += red[r][t];
    atomicAdd(&sums[t], v);
  }
  __syncthreads();
#pragma unroll
  for (int j = 0; j < 8; ++j) red[g][l16 * 8 + j] = sQ[j];
  __syncthreads();
  if (t < D) {
    float v = 0.f;
#pragma unroll
    for (int r = 0; r < 16; ++r) v += red[r][t];
    atomicAdd(&sums[D + t], v);
  }
}

// f32-output variant (used when ws lacks room for agb)
__global__ __launch_bounds__(256) void csr_agg_stats_kernel(
    const int* __restrict__ csr_row, const int* __restrict__ offsets,
    const float* __restrict__ dis, const uint4* __restrict__ hb,
    float* __restrict__ out, float* __restrict__ sums, int N, int E) {
  int t   = threadIdx.x;
  int l16 = t & 15;
  int g   = t >> 4;
  int qid = blockIdx.x * 16 + g;
  int qstride = gridDim.x * 16;
  float sA[8] = {}, sQ[8] = {};

  for (int c = qid; c < N; c += qstride) {
    int s = offsets[c];
    int e = (c + 1 < N) ? offsets[c + 1] : E;
    float acc[8] = {};
    for (int i = s; i < e; ++i) {
      int r = csr_row[i];
      uint4 v = hb[(size_t)r * 16 + l16];
      add8(acc, v);
    }
    float wc = dis[c];
    float v0 = acc[0]*wc, v1 = acc[1]*wc, v2 = acc[2]*wc, v3 = acc[3]*wc;
    float v4 = acc[4]*wc, v5 = acc[5]*wc, v6 = acc[6]*wc, v7 = acc[7]*wc;
    ((float4*)out)[(size_t)c * 32 + l16 * 2]     = make_float4(v0, v1, v2, v3);
    ((float4*)out)[(size_t)c * 32 + l16 * 2 + 1] = make_float4(v4, v5, v6, v7);
    sA[0]+=v0; sA[1]+=v1; sA[2]+=v2; sA[3]+=v3;
    sA[4]+=v4; sA[5]+=v5; sA[6]+=v6; sA[7]+=v7;
    sQ[0]+=v0*v0; sQ[1]+=v1*v1; sQ[2]+=v2*v2; sQ[3]+=v3*v3;
    sQ[4]+=v4*v4; sQ[5]+=v5*v5; sQ[6]+=v6*v6; sQ[7]+=v7*v7;
  }

  __shared__ float red[16][D];
#pragma unroll
  for (int j = 0; j < 8; ++j) red[g][l16 * 8 + j] = sA[j];
  __syncthreads();
  if (t < D) {
    float v = 0.f;
#pragma unroll
    for (int r = 0; r < 16; ++r) v += red[r][t];
    atomicAdd(&sums[t], v);
  }
  __syncthreads();
#pragma unroll
  for (int j = 0; j < 8; ++j) red[g][l16 * 8 + j] = sQ[j];
  __syncthreads();
  if (t < D) {
    float v = 0.f;
#pragma unroll
    for (int r = 0; r < 16; ++r) v += red[r][t];
    atomicAdd(&sums[D + t], v);
  }
}

// ============== f32 gather fallback (round-4 proven version) ===============
__global__ __launch_bounds__(256) void csr_agg_kernel(
    const int* __restrict__ csr_row, const int* __restrict__ offsets,
    const float* __restrict__ dis, const float* __restrict__ x,
    float* __restrict__ out, int N, int E) {
  int wave = threadIdx.x >> 6;
  int lane = threadIdx.x & 63;
  int half = lane >> 5;
  int d4   = lane & 31;
  int c = blockIdx.x * 4 + wave;
  if (c >= N) return;
  int s = offsets[c];
  int e = (c + 1 < N) ? offsets[c + 1] : E;
  const float4* x4 = (const float4*)x;
  float4 a0 = {0.f, 0.f, 0.f, 0.f};
  int i = s + half;
  for (; i < e; i += 2) {
    int r = csr_row[i];
    float w = dis[r];
    float4 v = x4[(size_t)r * 32 + d4];
    a0.x = fmaf(w, v.x, a0.x); a0.y = fmaf(w, v.y, a0.y);
    a0.z = fmaf(w, v.z, a0.z); a0.w = fmaf(w, v.w, a0.w);
  }
  a0.x += __shfl_xor(a0.x, 32, 64);
  a0.y += __shfl_xor(a0.y, 32, 64);
  a0.z += __shfl_xor(a0.z, 32, 64);
  a0.w += __shfl_xor(a0.w, 32, 64);
  if (half == 0) {
    float wc = dis[c];
    a0.x *= wc; a0.y *= wc; a0.z *= wc; a0.w *= wc;
    ((float4*)out)[(size_t)c * 32 + d4] = a0;
  }
}

// ====================== fallback aggregation (atomics) =====================
__global__ __launch_bounds__(256) void degree_f_kernel(
    const int* __restrict__ col, float* __restrict__ deg, int E) {
  int e = blockIdx.x * 256 + threadIdx.x;
  if (e < E) atomicAdd(&deg[col[e]], 1.0f);
}
__global__ __launch_bounds__(256) void dis_kernel(float* __restrict__ deg, int N) {
  int n = blockIdx.x * 256 + threadIdx.x;
  if (n < N) {
    float d = deg[n];
    deg[n] = (d > 0.0f) ? rsqrtf(fmaxf(d, 1.0f)) : 0.0f;
  }
}
__global__ __launch_bounds__(256) void scatter_kernel(
    const int* __restrict__ ei, const float* __restrict__ x,
    const float* __restrict__ dis, float* __restrict__ out, int E) {
  int e = blockIdx.x * 2 + (threadIdx.x >> 7);
  int d = threadIdx.x & 127;
  if (e >= E) return;
  int r = ei[e];
  int c = ei[E + e];
  float norm = dis[r] * dis[c];
  atomicAdd(&out[(size_t)c * D + d], x[(size_t)r * D + d] * norm);
}

// ======= fallback in-place f32 GEMM + fused BN stats (round-6 proven) ======
__global__ __launch_bounds__(256) void gemm_stats_kernel(
    const float* __restrict__ W, float* __restrict__ out,
    float* __restrict__ sums, int N) {
  __shared__ float Wl[D * D];
  __shared__ float4 xs4[GEMM_TILE][D / 4];
  int t = threadIdx.x;
  {
    const float4* W4 = (const float4*)W;
    float4* Wl4w = (float4*)Wl;
#pragma unroll
    for (int i = 0; i < 16; ++i)
      Wl4w[i * 256 + t] = W4[i * 256 + t];
  }
  const float4* Wl4 = (const float4*)Wl;
  const float4* o4r = (const float4*)out;
  float4* o4w = (float4*)out;
  int rp = t >> 5;
  int cq = t & 31;
  int r0 = rp * 4;
  float sA0=0,sA1=0,sA2=0,sA3=0, sQ0=0,sQ1=0,sQ2=0,sQ3=0;
  size_t total4 = (size_t)N * 32;
  float4 pf[4];
  int base = blockIdx.x * GEMM_TILE;
#pragma unroll
  for (int i = 0; i < 4; ++i) {
    size_t idx = (size_t)base * 32 + t + i * 256;
    pf[i] = (idx < total4) ? o4r[idx] : make_float4(0.f, 0.f, 0.f, 0.f);
  }
  for (; base < N; base += GEMM_GRID * GEMM_TILE) {
    __syncthreads();
#pragma unroll
    for (int i = 0; i < 4; ++i)
      ((float4*)xs4)[t + i * 256] = pf[i];
    __syncthreads();
    int nbase = base + GEMM_GRID * GEMM_TILE;
    if (nbase < N) {
#pragma unroll
      for (int i = 0; i < 4; ++i) {
        size_t idx = (size_t)nbase * 32 + t + i * 256;
        pf[i] = (idx < total4) ? o4r[idx] : make_float4(0.f, 0.f, 0.f, 0.f);
      }
    }
    int nrows = min(GEMM_TILE, N - base);
    float acc[4][4] = {};
    for (int k4 = 0; k4 < 32; ++k4) {
      float4 wv0 = Wl4[(k4 * 4 + 0) * 32 + cq];
      float4 wv1 = Wl4[(k4 * 4 + 1) * 32 + cq];
      float4 wv2 = Wl4[(k4 * 4 + 2) * 32 + cq];
      float4 wv3 = Wl4[(k4 * 4 + 3) * 32 + cq];
#pragma unroll
      for (int rr = 0; rr < 4; ++rr) {
        float4 xv = xs4[r0 + rr][k4];
        acc[rr][0] = fmaf(xv.x, wv0.x, acc[rr][0]);
        acc[rr][1] = fmaf(xv.x, wv0.y, acc[rr][1]);
        acc[rr][2] = fmaf(xv.x, wv0.z, acc[rr][2]);
        acc[rr][3] = fmaf(xv.x, wv0.w, acc[rr][3]);
        acc[rr][0] = fmaf(xv.y, wv1.x, acc[rr][0]);
        acc[rr][1] = fmaf(xv.y, wv1.y, acc[rr][1]);
        acc[rr][2] = fmaf(xv.y, wv1.z, acc[rr][2]);
        acc[rr][3] = fmaf(xv.y, wv1.w, acc[rr][3]);
        acc[rr][0] = fmaf(xv.z, wv2.x, acc[rr][0]);
        acc[rr][1] = fmaf(xv.z, wv2.y, acc[rr][1]);
        acc[rr][2] = fmaf(xv.z, wv2.z, acc[rr][2]);
        acc[rr][3] = fmaf(xv.z, wv2.w, acc[rr][3]);
        acc[rr][0] = fmaf(xv.w, wv3.x, acc[rr][0]);
        acc[rr][1] = fmaf(xv.w, wv3.y, acc[rr][1]);
        acc[rr][2] = fmaf(xv.w, wv3.z, acc[rr][2]);
        acc[rr][3] = fmaf(xv.w, wv3.w, acc[rr][3]);
      }
    }
#pragma unroll
    for (int rr = 0; rr < 4; ++rr) {
      if (r0 + rr < nrows) {
        o4w[(size_t)(base + r0 + rr) * 32 + cq] =
            make_float4(acc[rr][0], acc[rr][1], acc[rr][2], acc[rr][3]);
        sA0 += acc[rr][0]; sA1 += acc[rr][1]; sA2 += acc[rr][2]; sA3 += acc[rr][3];
        sQ0 += acc[rr][0]*acc[rr][0]; sQ1 += acc[rr][1]*acc[rr][1];
        sQ2 += acc[rr][2]*acc[rr][2]; sQ3 += acc[rr][3]*acc[rr][3];
      }
    }
  }
  float4* red = (float4*)xs4;
  __syncthreads();
  red[t] = make_float4(sA0, sA1, sA2, sA3);
  __syncthreads();
  if (rp == 0) {
    float4 v = red[cq];
#pragma unroll
    for (int r = 1; r < 8; ++r) {
      float4 u = red[r * 32 + cq];
      v.x += u.x; v.y += u.y; v.z += u.z; v.w += u.w;
    }
    atomicAdd(&sums[4 * cq + 0], v.x);
    atomicAdd(&sums[4 * cq + 1], v.y);
    atomicAdd(&sums[4 * cq + 2], v.z);
    atomicAdd(&sums[4 * cq + 3], v.w);
  }
  __syncthreads();
  red[t] = make_float4(sQ0, sQ1, sQ2, sQ3);
  __syncthreads();
  if (rp == 0) {
    float4 v = red[cq];
#pragma unroll
    for (int r = 1; r < 8; ++r) {
      float4 u = red[r * 32 + cq];
      v.x += u.x; v.y += u.y; v.z += u.z; v.w += u.w;
    }
    atomicAdd(&sums[D + 4 * cq + 0], v.x);
    atomicAdd(&sums[D + 4 * cq + 1], v.y);
    atomicAdd(&sums[D + 4 * cq + 2], v.z);
    atomicAdd(&sums[D + 4 * cq + 3], v.w);
  }
}

// ====== final: BN-finalize + norm + ReLU + residual, regs per thread =======
__global__ __launch_bounds__(256) void final_fused_kernel(
    const float* __restrict__ x, const uint4* __restrict__ agb,
    const float* __restrict__ sums, const float* __restrict__ gamma,
    const float* __restrict__ beta, float* __restrict__ out, int N) {
  int t = threadIdx.x;
  int l16 = t & 15;
  int d0 = l16 * 8;
  float sc[8], sh[8];
  float inv_n = 1.0f / (float)N;
#pragma unroll
  for (int j = 0; j < 8; ++j) {
    int d = d0 + j;
    float mean = sums[d] * inv_n;
    float var = sums[D + d] * inv_n - mean * mean;
    float isd = rsqrtf(fmaxf(var, 0.0f) + BN_EPS);
    float s = isd * gamma[d];
    sc[j] = s;
    sh[j] = beta[d] - mean * s;
  }
  int nstride = gridDim.x * 16;
  for (int n = blockIdx.x * 16 + (t >> 4); n < N; n += nstride) {
    size_t i = (size_t)n * 16 + l16;
    uint4 v = agb[i];
    float4 xa = ((const float4*)x)[i * 2];
    float4 xb = ((const float4*)x)[i * 2 + 1];
    float4 o0, o1;
    o0.x = fmaxf(fmaf(__uint_as_float(v.x << 16),         sc[0], sh[0]), 0.f) + xa.x;
    o0.y = fmaxf(fmaf(__uint_as_float(v.x & 0xffff0000u), sc[1], sh[1]), 0.f) + xa.y;
    o0.z = fmaxf(fmaf(__uint_as_float(v.y << 16),         sc[2], sh[2]), 0.f) + xa.z;
    o0.w = fmaxf(fmaf(__uint_as_float(v.y & 0xffff0000u), sc[3], sh[3]), 0.f) + xa.w;
    o1.x = fmaxf(fmaf(__uint_as_float(v.z << 16),         sc[4], sh[4]), 0.f) + xb.x;
    o1.y = fmaxf(fmaf(__uint_as_float(v.z & 0xffff0000u), sc[5], sh[5]), 0.f) + xb.y;
    o1.z = fmaxf(fmaf(__uint_as_float(v.w << 16),         sc[6], sh[6]), 0.f) + xb.z;
    o1.w = fmaxf(fmaf(__uint_as_float(v.w & 0xffff0000u), sc[7], sh[7]), 0.f) + xb.w;
    ((float4*)out)[i * 2]     = o0;
    ((float4*)out)[i * 2 + 1] = o1;
  }
}

// ====================== BN finalize + f32 epilogue (fallback) ==============
__global__ void bn_finalize_kernel(const float* __restrict__ sums,
                                   float* __restrict__ mv, int N) {
  int d = threadIdx.x;
  if (d < D) {
    float inv_n = 1.0f / (float)N;
    float mean = sums[d] * inv_n;
    float var = sums[D + d] * inv_n - mean * mean;
    mv[d] = mean;
    mv[D + d] = rsqrtf(fmaxf(var, 0.0f) + BN_EPS);
  }
}

__global__ __launch_bounds__(256) void final4_kernel(
    const float* __restrict__ x, const float* __restrict__ mv,
    const float* __restrict__ gamma, const float* __restrict__ beta,
    float* __restrict__ out, int total4) {
  int i = blockIdx.x * 256 + threadIdx.x;
  if (i >= total4) return;
  int q = i & 31;
  float4 m4 = ((const float4*)mv)[q];
  float4 s4 = ((const float4*)mv)[32 + q];
  float4 g4 = ((const float4*)gamma)[q];
  float4 b4 = ((const float4*)beta)[q];
  float4 v  = ((const float4*)out)[i];
  float4 xv = ((const float4*)x)[i];
  float4 r;
  r.x = fmaxf((v.x - m4.x) * s4.x * g4.x + b4.x, 0.f) + xv.x;
  r.y = fmaxf((v.y - m4.y) * s4.y * g4.y + b4.y, 0.f) + xv.y;
  r.z = fmaxf((v.z - m4.z) * s4.z * g4.z + b4.z, 0.f) + xv.z;
  r.w = fmaxf((v.w - m4.w) * s4.w * g4.w + b4.w, 0.f) + xv.w;
  ((float4*)out)[i] = r;
}

// ===========================================================================
extern "C" void kernel_launch(void* const* d_in, const int* in_sizes, int n_in,
                              void* d_out, int out_size, void* d_ws, size_t ws_size,
                              hipStream_t stream) {
  const float* x     = (const float*)d_in[0];
  const int*   ei    = (const int*)d_in[1];   // int32 (harness converts ints)
  const float* W     = (const float*)d_in[2];
  // d_in[3] = b : cancels in BatchNorm (constant per-feature shift), skipped.
  const float* gamma = (const float*)d_in[4];
  const float* beta  = (const float*)d_in[5];

  const int N = in_sizes[0] / D;   // 100000
  const int E = in_sizes[1] / 2;   // 600000
  const int NB = (N + 255) / 256;

  float* out = (float*)d_out;      // doubles as agg buffer (f32 paths)
  char* ws = (char*)d_ws;

  size_t need_csr  = ((size_t)3 * N + 512 + E + 4 * D) * 4;
  size_t need_full = need_csr + (size_t)D * D * 2 + (size_t)N * D * 2;
  size_t need_agb  = need_full + (size_t)N * D * 2;

  if (ws_size >= need_csr && NB <= 512) {
    int*   cnt      = (int*)ws;               // N (reused as bucket cursor)
    int*   offsets  = cnt + N;                // N
    float* dis      = (float*)(offsets + N);  // N
    int*   partials = (int*)(dis + N);        // 512
    int*   csr_row  = partials + 512;         // E
    float* sums     = (float*)(csr_row + E);  // 2D
    float* mv       = sums + 2 * D;           // 2D
    unsigned short* Wt  = (unsigned short*)(mv + 2 * D);  // D*D bf16
    unsigned short* hb  = Wt + (size_t)D * D;             // N*D bf16
    unsigned short* agb = hb + (size_t)N * D;             // N*D bf16

    hipMemsetAsync(cnt, 0, (size_t)N * sizeof(int), stream);
    hipMemsetAsync(sums, 0, 2 * D * sizeof(float), stream);

    degree_i_kernel<<<(E + 255) / 256, 256, 0, stream>>>(ei + E, cnt, E);
    scanA_kernel<<<NB, 256, 0, stream>>>(cnt, dis, partials, N);
    scanB_kernel<<<1, 512, 0, stream>>>(partials, NB);
    scanC_kernel<<<NB, 256, 0, stream>>>(cnt, partials, offsets, N);
    hipMemsetAsync(cnt, 0, (size_t)N * sizeof(int), stream);  // -> cursor
    bucket_kernel<<<(E + 255) / 256, 256, 0, stream>>>(ei, offsets, cnt, csr_row, E);

    if (ws_size >= need_full) {
      cvt_w_kernel<<<64, 256, 0, stream>>>(W, Wt);
      gemm_mfma_kernel<<<MFMA_GRID, 256, 0, stream>>>(x, Wt, dis, hb, N);
      int nagg = min(AGG_BLOCKS, (N + 15) / 16);
      if (ws_size >= need_agb) {
        int ntiles = (N + (1 << TILE_SHIFT) - 1) >> TILE_SHIFT;
        csr_agg_tiled_kernel<<<nagg, 256, 0, stream>>>(
            csr_row, offsets, dis, (const uint4*)hb, (uint4*)agb, sums, N, E, ntiles);
        final_fused_kernel<<<2048, 256, 0, stream>>>(
            x, (const uint4*)agb, sums, gamma, beta, out, N);
      } else {
        csr_agg_stats_kernel<<<nagg, 256, 0, stream>>>(
            csr_row, offsets, dis, (const uint4*)hb, out, sums, N, E);
        bn_finalize_kernel<<<1, 128, 0, stream>>>(sums, mv, N);
        final4_kernel<<<(N * 32 + 255) / 256, 256, 0, stream>>>(
            x, mv, gamma, beta, out, N * 32);
      }
    } else {
      csr_agg_kernel<<<(N + 3) / 4, 256, 0, stream>>>(csr_row, offsets, dis, x, out, N, E);
      gemm_stats_kernel<<<GEMM_GRID, 256, 0, stream>>>(W, out, sums, N);
      bn_finalize_kernel<<<1, 128, 0, stream>>>(sums, mv, N);
      final4_kernel<<<(N * 32 + 255) / 256, 256, 0, stream>>>(
          x, mv, gamma, beta, out, N * 32);
    }
  } else {
    // ---- fallback: proven atomic-scatter path ----
    float* deg  = (float*)ws;
    float* sums = deg + N;
    float* mv   = sums + 2 * D;
    hipMemsetAsync(deg, 0, (size_t)N * sizeof(float), stream);
    hipMemsetAsync(sums, 0, 2 * D * sizeof(float), stream);
    hipMemsetAsync(out, 0, (size_t)out_size * sizeof(float), stream);
    degree_f_kernel<<<(E + 255) / 256, 256, 0, stream>>>(ei + E, deg, E);
    dis_kernel<<<(N + 255) / 256, 256, 0, stream>>>(deg, N);
    scatter_kernel<<<(E + 1) / 2, 256, 0, stream>>>(ei, x, deg, out, E);
    gemm_stats_kernel<<<GEMM_GRID, 256, 0, stream>>>(W, out, sums, N);
    bn_finalize_kernel<<<1, 128, 0, stream>>>(sums, mv, N);
    final4_kernel<<<(N * 32 + 255) / 256, 256, 0, stream>>>(x, mv, gamma, beta, out, N * 32);
  }
}

// Round 14
// 188.297 us; speedup vs baseline: 1.2404x; 1.2404x over previous
//
#include <hip/hip_runtime.h>

#define D 128
#define BN_EPS 1e-5f
#define GEMM_GRID 512
#define GEMM_TILE 32
#define AGG_BLOCKS 2048

typedef __attribute__((ext_vector_type(8))) short short8v;   // 8 bf16 (4 VGPR)
typedef __attribute__((ext_vector_type(4))) float float4v;   // MFMA C/D

__device__ __forceinline__ unsigned int f2bf(float f) {      // f32 -> bf16 RNE
  unsigned int bits = __float_as_uint(f);
  return (bits + 0x7fffu + ((bits >> 16) & 1u)) >> 16;
}

__device__ __forceinline__ void add8(float* acc, uint4 v) {  // acc += bf16x8
  acc[0] += __uint_as_float(v.x << 16);
  acc[1] += __uint_as_float(v.x & 0xffff0000u);
  acc[2] += __uint_as_float(v.y << 16);
  acc[3] += __uint_as_float(v.y & 0xffff0000u);
  acc[4] += __uint_as_float(v.z << 16);
  acc[5] += __uint_as_float(v.z & 0xffff0000u);
  acc[6] += __uint_as_float(v.w << 16);
  acc[7] += __uint_as_float(v.w & 0xffff0000u);
}

// ==================== CSR build (ordered 3-kernel scan) ====================
__global__ __launch_bounds__(256) void degree_i_kernel(
    const int* __restrict__ col, int* __restrict__ cnt, int E) {
  int e = blockIdx.x * 256 + threadIdx.x;
  if (e < E) atomicAdd(&cnt[col[e]], 1);
}

__global__ __launch_bounds__(256) void scanA_kernel(
    const int* __restrict__ cnt, float* __restrict__ dis,
    int* __restrict__ partials, int N) {
  __shared__ int l[256];
  int t = threadIdx.x;
  int i = blockIdx.x * 256 + t;
  int v = (i < N) ? cnt[i] : 0;
  if (i < N) dis[i] = (v > 0) ? rsqrtf((float)v) : 0.0f;
  l[t] = v; __syncthreads();
  for (int s = 128; s > 0; s >>= 1) {
    if (t < s) l[t] += l[t + s];
    __syncthreads();
  }
  if (t == 0) partials[blockIdx.x] = l[0];
}

__global__ void scanB_kernel(int* __restrict__ partials, int nb) {
  __shared__ int l[512];
  int t = threadIdx.x;
  l[t] = (t < nb) ? partials[t] : 0;
  __syncthreads();
  for (int off = 1; off < 512; off <<= 1) {
    int v = (t >= off) ? l[t - off] : 0;
    __syncthreads();
    l[t] += v;
    __syncthreads();
  }
  if (t < nb) partials[t] = (t == 0) ? 0 : l[t - 1];
}

__global__ __launch_bounds__(256) void scanC_kernel(
    const int* __restrict__ cnt, const int* __restrict__ partials,
    int* __restrict__ offsets, int N) {
  __shared__ int l[256];
  int t = threadIdx.x;
  int i = blockIdx.x * 256 + t;
  int v = (i < N) ? cnt[i] : 0;
  l[t] = v; __syncthreads();
  for (int off = 1; off < 256; off <<= 1) {
    int u = (t >= off) ? l[t - off] : 0;
    __syncthreads();
    l[t] += u;
    __syncthreads();
  }
  if (i < N) offsets[i] = partials[blockIdx.x] + l[t] - v;
}

__global__ __launch_bounds__(256) void bucket_kernel(
    const int* __restrict__ ei, const int* __restrict__ offsets,
    int* __restrict__ cursor, int* __restrict__ csr_row, int E) {
  int e = blockIdx.x * 256 + threadIdx.x;
  if (e < E) {
    int c = ei[E + e];
    int p = offsets[c] + atomicAdd(&cursor[c], 1);
    csr_row[p] = ei[e];
  }
}

// ==================== W -> Wt bf16 (transposed) ============================
__global__ __launch_bounds__(256) void cvt_w_kernel(
    const float* __restrict__ W, unsigned short* __restrict__ Wt) {
  int idx = blockIdx.x * 256 + threadIdx.x;   // grid 64 -> 16384
  int k = idx >> 7, n = idx & 127;
  Wt[n * D + k] = (unsigned short)f2bf(W[idx]);
}

// ====== h' = dis .* (x @ W) via bf16 MFMA, bf16 out, 1 tile/block ==========
// block = 256 thr = 4 waves; tile = 64 rows x 128 cols; K = 128.
// Wt staged in 32KB LDS, XOR-swizzled (u ^= (n&7)<<3).
__global__ __launch_bounds__(256) void gemm_mfma_kernel(
    const float* __restrict__ x, const unsigned short* __restrict__ Wt,
    const float* __restrict__ dis, unsigned short* __restrict__ hb, int N) {
  __shared__ unsigned short Wl[D * D];        // 32 KB
  int t = threadIdx.x;
  {
    const uint4* src = (const uint4*)Wt;
    uint4* dst = (uint4*)Wl;
#pragma unroll
    for (int i = 0; i < 8; ++i) {
      int idx = t + i * 256;                  // uint4 index; row n = idx>>4
      dst[idx ^ ((idx >> 4) & 7)] = src[idx];
    }
  }
  __syncthreads();
  int wave = t >> 6, lane = t & 63;
  int r16 = lane & 15, kg = lane >> 4;        // A-row / k-group within frag
  int tilebase = blockIdx.x * 64 + wave * 16;
  int arow = tilebase + r16;
  bool rowok = arow < N;
  const float4* x4 = (const float4*)x;

  short8v afrag[4];
#pragma unroll
  for (int kc = 0; kc < 4; ++kc) {
    float4 lo = make_float4(0.f, 0.f, 0.f, 0.f);
    float4 hi = make_float4(0.f, 0.f, 0.f, 0.f);
    if (rowok) {
      lo = x4[(size_t)arow * 32 + kc * 8 + kg * 2];
      hi = x4[(size_t)arow * 32 + kc * 8 + kg * 2 + 1];
    }
    short8v a;
    a[0] = (short)f2bf(lo.x); a[1] = (short)f2bf(lo.y);
    a[2] = (short)f2bf(lo.z); a[3] = (short)f2bf(lo.w);
    a[4] = (short)f2bf(hi.x); a[5] = (short)f2bf(hi.y);
    a[6] = (short)f2bf(hi.z); a[7] = (short)f2bf(hi.w);
    afrag[kc] = a;
  }

  float dv[4];
#pragma unroll
  for (int reg = 0; reg < 4; ++reg) {
    int r = tilebase + kg * 4 + reg;
    dv[reg] = (r < N) ? dis[r] : 0.f;
  }

#pragma unroll
  for (int ct = 0; ct < 8; ++ct) {            // 8 col-tiles of 16
    float4v c = {0.f, 0.f, 0.f, 0.f};
    int n = ct * 16 + r16;                    // B col this lane loads
#pragma unroll
    for (int kc = 0; kc < 4; ++kc) {
      int u = (n * D + kc * 32 + kg * 8) ^ ((n & 7) << 3);
      short8v b = *(const short8v*)&Wl[u];
      c = __builtin_amdgcn_mfma_f32_16x16x32_bf16(afrag[kc], b, c, 0, 0, 0);
    }
    // C/D layout (m89-verified): col = lane&15, row = (lane>>4)*4 + reg
#pragma unroll
    for (int reg = 0; reg < 4; ++reg) {
      int r = tilebase + kg * 4 + reg;
      if (r < N)
        hb[(size_t)r * D + ct * 16 + r16] = (unsigned short)f2bf(c[reg] * dv[reg]);
    }
  }
}

// ====== aggregation (bf16 gather) + fused BN stats, quarter-per-node =======
// Ordered CSR: segment end = offsets[c+1].  Writes bf16 agb (half traffic).
__global__ __launch_bounds__(256) void csr_agg_stats_bf16_kernel(
    const int* __restrict__ csr_row, const int* __restrict__ offsets,
    const float* __restrict__ dis, const uint4* __restrict__ hb,
    uint4* __restrict__ agb, float* __restrict__ sums, int N, int E) {
  int t   = threadIdx.x;
  int l16 = t & 15;
  int g   = t >> 4;
  int qid = blockIdx.x * 16 + g;
  int qstride = gridDim.x * 16;
  float sA[8] = {}, sQ[8] = {};

  for (int c = qid; c < N; c += qstride) {
    int s = offsets[c];
    int e = (c + 1 < N) ? offsets[c + 1] : E;
    float acc[8] = {};
    int i = s;
    for (; i + 3 < e; i += 4) {
      int r0 = csr_row[i];
      int r1 = csr_row[i + 1];
      int r2 = csr_row[i + 2];
      int r3 = csr_row[i + 3];
      uint4 v0 = hb[(size_t)r0 * 16 + l16];
      uint4 v1 = hb[(size_t)r1 * 16 + l16];
      uint4 v2 = hb[(size_t)r2 * 16 + l16];
      uint4 v3 = hb[(size_t)r3 * 16 + l16];
      add8(acc, v0); add8(acc, v1); add8(acc, v2); add8(acc, v3);
    }
    if (i + 1 < e) {
      int r0 = csr_row[i];
      int r1 = csr_row[i + 1];
      uint4 v0 = hb[(size_t)r0 * 16 + l16];
      uint4 v1 = hb[(size_t)r1 * 16 + l16];
      add8(acc, v0); add8(acc, v1);
      i += 2;
    }
    if (i < e) {
      int r = csr_row[i];
      uint4 v = hb[(size_t)r * 16 + l16];
      add8(acc, v);
    }
    float wc = dis[c];
    float v0 = acc[0]*wc, v1 = acc[1]*wc, v2 = acc[2]*wc, v3 = acc[3]*wc;
    float v4 = acc[4]*wc, v5 = acc[5]*wc, v6 = acc[6]*wc, v7 = acc[7]*wc;
    uint4 o;
    o.x = f2bf(v0) | (f2bf(v1) << 16);
    o.y = f2bf(v2) | (f2bf(v3) << 16);
    o.z = f2bf(v4) | (f2bf(v5) << 16);
    o.w = f2bf(v6) | (f2bf(v7) << 16);
    agb[(size_t)c * 16 + l16] = o;
    sA[0]+=v0; sA[1]+=v1; sA[2]+=v2; sA[3]+=v3;
    sA[4]+=v4; sA[5]+=v5; sA[6]+=v6; sA[7]+=v7;
    sQ[0]+=v0*v0; sQ[1]+=v1*v1; sQ[2]+=v2*v2; sQ[3]+=v3*v3;
    sQ[4]+=v4*v4; sQ[5]+=v5*v5; sQ[6]+=v6*v6; sQ[7]+=v7*v7;
  }

  __shared__ float red[16][D];   // 8 KB
#pragma unroll
  for (int j = 0; j < 8; ++j) red[g][l16 * 8 + j] = sA[j];
  __syncthreads();
  if (t < D) {
    float v = 0.f;
#pragma unroll
    for (int r = 0; r < 16; ++r) v += red[r][t];
    atomicAdd(&sums[t], v);
  }
  __syncthreads();
#pragma unroll
  for (int j = 0; j < 8; ++j) red[g][l16 * 8 + j] = sQ[j];
  __syncthreads();
  if (t < D) {
    float v = 0.f;
#pragma unroll
    for (int r = 0; r < 16; ++r) v += red[r][t];
    atomicAdd(&sums[D + t], v);
  }
}

// f32-output variant (used when ws lacks room for agb)
__global__ __launch_bounds__(256) void csr_agg_stats_kernel(
    const int* __restrict__ csr_row, const int* __restrict__ offsets,
    const float* __restrict__ dis, const uint4* __restrict__ hb,
    float* __restrict__ out, float* __restrict__ sums, int N, int E) {
  int t   = threadIdx.x;
  int l16 = t & 15;
  int g   = t >> 4;
  int qid = blockIdx.x * 16 + g;
  int qstride = gridDim.x * 16;
  float sA[8] = {}, sQ[8] = {};

  for (int c = qid; c < N; c += qstride) {
    int s = offsets[c];
    int e = (c + 1 < N) ? offsets[c + 1] : E;
    float acc[8] = {};
    for (int i = s; i < e; ++i) {
      int r = csr_row[i];
      uint4 v = hb[(size_t)r * 16 + l16];
      add8(acc, v);
    }
    float wc = dis[c];
    float v0 = acc[0]*wc, v1 = acc[1]*wc, v2 = acc[2]*wc, v3 = acc[3]*wc;
    float v4 = acc[4]*wc, v5 = acc[5]*wc, v6 = acc[6]*wc, v7 = acc[7]*wc;
    ((float4*)out)[(size_t)c * 32 + l16 * 2]     = make_float4(v0, v1, v2, v3);
    ((float4*)out)[(size_t)c * 32 + l16 * 2 + 1] = make_float4(v4, v5, v6, v7);
    sA[0]+=v0; sA[1]+=v1; sA[2]+=v2; sA[3]+=v3;
    sA[4]+=v4; sA[5]+=v5; sA[6]+=v6; sA[7]+=v7;
    sQ[0]+=v0*v0; sQ[1]+=v1*v1; sQ[2]+=v2*v2; sQ[3]+=v3*v3;
    sQ[4]+=v4*v4; sQ[5]+=v5*v5; sQ[6]+=v6*v6; sQ[7]+=v7*v7;
  }

  __shared__ float red[16][D];
#pragma unroll
  for (int j = 0; j < 8; ++j) red[g][l16 * 8 + j] = sA[j];
  __syncthreads();
  if (t < D) {
    float v = 0.f;
#pragma unroll
    for (int r = 0; r < 16; ++r) v += red[r][t];
    atomicAdd(&sums[t], v);
  }
  __syncthreads();
#pragma unroll
  for (int j = 0; j < 8; ++j) red[g][l16 * 8 + j] = sQ[j];
  __syncthreads();
  if (t < D) {
    float v = 0.f;
#pragma unroll
    for (int r = 0; r < 16; ++r) v += red[r][t];
    atomicAdd(&sums[D + t], v);
  }
}

// ============== f32 gather fallback (round-4 proven version) ===============
__global__ __launch_bounds__(256) void csr_agg_kernel(
    const int* __restrict__ csr_row, const int* __restrict__ offsets,
    const float* __restrict__ dis, const float* __restrict__ x,
    float* __restrict__ out, int N, int E) {
  int wave = threadIdx.x >> 6;
  int lane = threadIdx.x & 63;
  int half = lane >> 5;
  int d4   = lane & 31;
  int c = blockIdx.x * 4 + wave;
  if (c >= N) return;
  int s = offsets[c];
  int e = (c + 1 < N) ? offsets[c + 1] : E;
  const float4* x4 = (const float4*)x;
  float4 a0 = {0.f, 0.f, 0.f, 0.f};
  int i = s + half;
  for (; i < e; i += 2) {
    int r = csr_row[i];
    float w = dis[r];
    float4 v = x4[(size_t)r * 32 + d4];
    a0.x = fmaf(w, v.x, a0.x); a0.y = fmaf(w, v.y, a0.y);
    a0.z = fmaf(w, v.z, a0.z); a0.w = fmaf(w, v.w, a0.w);
  }
  a0.x += __shfl_xor(a0.x, 32, 64);
  a0.y += __shfl_xor(a0.y, 32, 64);
  a0.z += __shfl_xor(a0.z, 32, 64);
  a0.w += __shfl_xor(a0.w, 32, 64);
  if (half == 0) {
    float wc = dis[c];
    a0.x *= wc; a0.y *= wc; a0.z *= wc; a0.w *= wc;
    ((float4*)out)[(size_t)c * 32 + d4] = a0;
  }
}

// ====================== fallback aggregation (atomics) =====================
__global__ __launch_bounds__(256) void degree_f_kernel(
    const int* __restrict__ col, float* __restrict__ deg, int E) {
  int e = blockIdx.x * 256 + threadIdx.x;
  if (e < E) atomicAdd(&deg[col[e]], 1.0f);
}
__global__ __launch_bounds__(256) void dis_kernel(float* __restrict__ deg, int N) {
  int n = blockIdx.x * 256 + threadIdx.x;
  if (n < N) {
    float d = deg[n];
    deg[n] = (d > 0.0f) ? rsqrtf(fmaxf(d, 1.0f)) : 0.0f;
  }
}
__global__ __launch_bounds__(256) void scatter_kernel(
    const int* __restrict__ ei, const float* __restrict__ x,
    const float* __restrict__ dis, float* __restrict__ out, int E) {
  int e = blockIdx.x * 2 + (threadIdx.x >> 7);
  int d = threadIdx.x & 127;
  if (e >= E) return;
  int r = ei[e];
  int c = ei[E + e];
  float norm = dis[r] * dis[c];
  atomicAdd(&out[(size_t)c * D + d], x[(size_t)r * D + d] * norm);
}

// ======= fallback in-place f32 GEMM + fused BN stats (round-6 proven) ======
__global__ __launch_bounds__(256) void gemm_stats_kernel(
    const float* __restrict__ W, float* __restrict__ out,
    float* __restrict__ sums, int N) {
  __shared__ float Wl[D * D];
  __shared__ float4 xs4[GEMM_TILE][D / 4];
  int t = threadIdx.x;
  {
    const float4* W4 = (const float4*)W;
    float4* Wl4w = (float4*)Wl;
#pragma unroll
    for (int i = 0; i < 16; ++i)
      Wl4w[i * 256 + t] = W4[i * 256 + t];
  }
  const float4* Wl4 = (const float4*)Wl;
  const float4* o4r = (const float4*)out;
  float4* o4w = (float4*)out;
  int rp = t >> 5;
  int cq = t & 31;
  int r0 = rp * 4;
  float sA0=0,sA1=0,sA2=0,sA3=0, sQ0=0,sQ1=0,sQ2=0,sQ3=0;
  size_t total4 = (size_t)N * 32;
  float4 pf[4];
  int base = blockIdx.x * GEMM_TILE;
#pragma unroll
  for (int i = 0; i < 4; ++i) {
    size_t idx = (size_t)base * 32 + t + i * 256;
    pf[i] = (idx < total4) ? o4r[idx] : make_float4(0.f, 0.f, 0.f, 0.f);
  }
  for (; base < N; base += GEMM_GRID * GEMM_TILE) {
    __syncthreads();
#pragma unroll
    for (int i = 0; i < 4; ++i)
      ((float4*)xs4)[t + i * 256] = pf[i];
    __syncthreads();
    int nbase = base + GEMM_GRID * GEMM_TILE;
    if (nbase < N) {
#pragma unroll
      for (int i = 0; i < 4; ++i) {
        size_t idx = (size_t)nbase * 32 + t + i * 256;
        pf[i] = (idx < total4) ? o4r[idx] : make_float4(0.f, 0.f, 0.f, 0.f);
      }
    }
    int nrows = min(GEMM_TILE, N - base);
    float acc[4][4] = {};
    for (int k4 = 0; k4 < 32; ++k4) {
      float4 wv0 = Wl4[(k4 * 4 + 0) * 32 + cq];
      float4 wv1 = Wl4[(k4 * 4 + 1) * 32 + cq];
      float4 wv2 = Wl4[(k4 * 4 + 2) * 32 + cq];
      float4 wv3 = Wl4[(k4 * 4 + 3) * 32 + cq];
#pragma unroll
      for (int rr = 0; rr < 4; ++rr) {
        float4 xv = xs4[r0 + rr][k4];
        acc[rr][0] = fmaf(xv.x, wv0.x, acc[rr][0]);
        acc[rr][1] = fmaf(xv.x, wv0.y, acc[rr][1]);
        acc[rr][2] = fmaf(xv.x, wv0.z, acc[rr][2]);
        acc[rr][3] = fmaf(xv.x, wv0.w, acc[rr][3]);
        acc[rr][0] = fmaf(xv.y, wv1.x, acc[rr][0]);
        acc[rr][1] = fmaf(xv.y, wv1.y, acc[rr][1]);
        acc[rr][2] = fmaf(xv.y, wv1.z, acc[rr][2]);
        acc[rr][3] = fmaf(xv.y, wv1.w, acc[rr][3]);
        acc[rr][0] = fmaf(xv.z, wv2.x, acc[rr][0]);
        acc[rr][1] = fmaf(xv.z, wv2.y, acc[rr][1]);
        acc[rr][2] = fmaf(xv.z, wv2.z, acc[rr][2]);
        acc[rr][3] = fmaf(xv.z, wv2.w, acc[rr][3]);
        acc[rr][0] = fmaf(xv.w, wv3.x, acc[rr][0]);
        acc[rr][1] = fmaf(xv.w, wv3.y, acc[rr][1]);
        acc[rr][2] = fmaf(xv.w, wv3.z, acc[rr][2]);
        acc[rr][3] = fmaf(xv.w, wv3.w, acc[rr][3]);
      }
    }
#pragma unroll
    for (int rr = 0; rr < 4; ++rr) {
      if (r0 + rr < nrows) {
        o4w[(size_t)(base + r0 + rr) * 32 + cq] =
            make_float4(acc[rr][0], acc[rr][1], acc[rr][2], acc[rr][3]);
        sA0 += acc[rr][0]; sA1 += acc[rr][1]; sA2 += acc[rr][2]; sA3 += acc[rr][3];
        sQ0 += acc[rr][0]*acc[rr][0]; sQ1 += acc[rr][1]*acc[rr][1];
        sQ2 += acc[rr][2]*acc[rr][2]; sQ3 += acc[rr][3]*acc[rr][3];
      }
    }
  }
  float4* red = (float4*)xs4;
  __syncthreads();
  red[t] = make_float4(sA0, sA1, sA2, sA3);
  __syncthreads();
  if (rp == 0) {
    float4 v = red[cq];
#pragma unroll
    for (int r = 1; r < 8; ++r) {
      float4 u = red[r * 32 + cq];
      v.x += u.x; v.y += u.y; v.z += u.z; v.w += u.w;
    }
    atomicAdd(&sums[4 * cq + 0], v.x);
    atomicAdd(&sums[4 * cq + 1], v.y);
    atomicAdd(&sums[4 * cq + 2], v.z);
    atomicAdd(&sums[4 * cq + 3], v.w);
  }
  __syncthreads();
  red[t] = make_float4(sQ0, sQ1, sQ2, sQ3);
  __syncthreads();
  if (rp == 0) {
    float4 v = red[cq];
#pragma unroll
    for (int r = 1; r < 8; ++r) {
      float4 u = red[r * 32 + cq];
      v.x += u.x; v.y += u.y; v.z += u.z; v.w += u.w;
    }
    atomicAdd(&sums[D + 4 * cq + 0], v.x);
    atomicAdd(&sums[D + 4 * cq + 1], v.y);
    atomicAdd(&sums[D + 4 * cq + 2], v.z);
    atomicAdd(&sums[D + 4 * cq + 3], v.w);
  }
}

// ====== final: BN-finalize + norm + ReLU + residual, regs per thread =======
__global__ __launch_bounds__(256) void final_fused_kernel(
    const float* __restrict__ x, const uint4* __restrict__ agb,
    const float* __restrict__ sums, const float* __restrict__ gamma,
    const float* __restrict__ beta, float* __restrict__ out, int N) {
  int t = threadIdx.x;
  int l16 = t & 15;
  int d0 = l16 * 8;
  float sc[8], sh[8];
  float inv_n = 1.0f / (float)N;
#pragma unroll
  for (int j = 0; j < 8; ++j) {
    int d = d0 + j;
    float mean = sums[d] * inv_n;
    float var = sums[D + d] * inv_n - mean * mean;
    float isd = rsqrtf(fmaxf(var, 0.0f) + BN_EPS);
    float s = isd * gamma[d];
    sc[j] = s;
    sh[j] = beta[d] - mean * s;
  }
  int nstride = gridDim.x * 16;
  for (int n = blockIdx.x * 16 + (t >> 4); n < N; n += nstride) {
    size_t i = (size_t)n * 16 + l16;
    uint4 v = agb[i];
    float4 xa = ((const float4*)x)[i * 2];
    float4 xb = ((const float4*)x)[i * 2 + 1];
    float4 o0, o1;
    o0.x = fmaxf(fmaf(__uint_as_float(v.x << 16),         sc[0], sh[0]), 0.f) + xa.x;
    o0.y = fmaxf(fmaf(__uint_as_float(v.x & 0xffff0000u), sc[1], sh[1]), 0.f) + xa.y;
    o0.z = fmaxf(fmaf(__uint_as_float(v.y << 16),         sc[2], sh[2]), 0.f) + xa.z;
    o0.w = fmaxf(fmaf(__uint_as_float(v.y & 0xffff0000u), sc[3], sh[3]), 0.f) + xa.w;
    o1.x = fmaxf(fmaf(__uint_as_float(v.z << 16),         sc[4], sh[4]), 0.f) + xb.x;
    o1.y = fmaxf(fmaf(__uint_as_float(v.z & 0xffff0000u), sc[5], sh[5]), 0.f) + xb.y;
    o1.z = fmaxf(fmaf(__uint_as_float(v.w << 16),         sc[6], sh[6]), 0.f) + xb.z;
    o1.w = fmaxf(fmaf(__uint_as_float(v.w & 0xffff0000u), sc[7], sh[7]), 0.f) + xb.w;
    ((float4*)out)[i * 2]     = o0;
    ((float4*)out)[i * 2 + 1] = o1;
  }
}

// ====================== BN finalize + f32 epilogue (fallback) ==============
__global__ void bn_finalize_kernel(const float* __restrict__ sums,
                                   float* __restrict__ mv, int N) {
  int d = threadIdx.x;
  if (d < D) {
    float inv_n = 1.0f / (float)N;
    float mean = sums[d] * inv_n;
    float var = sums[D + d] * inv_n - mean * mean;
    mv[d] = mean;
    mv[D + d] = rsqrtf(fmaxf(var, 0.0f) + BN_EPS);
  }
}

__global__ __launch_bounds__(256) void final4_kernel(
    const float* __restrict__ x, const float* __restrict__ mv,
    const float* __restrict__ gamma, const float* __restrict__ beta,
    float* __restrict__ out, int total4) {
  int i = blockIdx.x * 256 + threadIdx.x;
  if (i >= total4) return;
  int q = i & 31;
  float4 m4 = ((const float4*)mv)[q];
  float4 s4 = ((const float4*)mv)[32 + q];
  float4 g4 = ((const float4*)gamma)[q];
  float4 b4 = ((const float4*)beta)[q];
  float4 v  = ((const float4*)out)[i];
  float4 xv = ((const float4*)x)[i];
  float4 r;
  r.x = fmaxf((v.x - m4.x) * s4.x * g4.x + b4.x, 0.f) + xv.x;
  r.y = fmaxf((v.y - m4.y) * s4.y * g4.y + b4.y, 0.f) + xv.y;
  r.z = fmaxf((v.z - m4.z) * s4.z * g4.z + b4.z, 0.f) + xv.z;
  r.w = fmaxf((v.w - m4.w) * s4.w * g4.w + b4.w, 0.f) + xv.w;
  ((float4*)out)[i] = r;
}

// ===========================================================================
extern "C" void kernel_launch(void* const* d_in, const int* in_sizes, int n_in,
                              void* d_out, int out_size, void* d_ws, size_t ws_size,
                              hipStream_t stream) {
  const float* x     = (const float*)d_in[0];
  const int*   ei    = (const int*)d_in[1];   // int32 (harness converts ints)
  const float* W     = (const float*)d_in[2];
  // d_in[3] = b : cancels in BatchNorm (constant per-feature shift), skipped.
  const float* gamma = (const float*)d_in[4];
  const float* beta  = (const float*)d_in[5];

  const int N = in_sizes[0] / D;   // 100000
  const int E = in_sizes[1] / 2;   // 600000
  const int NB = (N + 255) / 256;

  float* out = (float*)d_out;      // doubles as agg buffer (f32 paths)
  char* ws = (char*)d_ws;

  size_t need_csr  = ((size_t)3 * N + 512 + E + 4 * D) * 4;
  size_t need_full = need_csr + (size_t)D * D * 2 + (size_t)N * D * 2;
  size_t need_agb  = need_full + (size_t)N * D * 2;

  if (ws_size >= need_csr && NB <= 512) {
    int*   cnt      = (int*)ws;               // N (reused as bucket cursor)
    int*   offsets  = cnt + N;                // N
    float* dis      = (float*)(offsets + N);  // N
    int*   partials = (int*)(dis + N);        // 512
    int*   csr_row  = partials + 512;         // E
    float* sums     = (float*)(csr_row + E);  // 2D
    float* mv       = sums + 2 * D;           // 2D
    unsigned short* Wt  = (unsigned short*)(mv + 2 * D);  // D*D bf16
    unsigned short* hb  = Wt + (size_t)D * D;             // N*D bf16
    unsigned short* agb = hb + (size_t)N * D;             // N*D bf16

    hipMemsetAsync(cnt, 0, (size_t)N * sizeof(int), stream);
    hipMemsetAsync(sums, 0, 2 * D * sizeof(float), stream);

    degree_i_kernel<<<(E + 255) / 256, 256, 0, stream>>>(ei + E, cnt, E);
    scanA_kernel<<<NB, 256, 0, stream>>>(cnt, dis, partials, N);
    scanB_kernel<<<1, 512, 0, stream>>>(partials, NB);
    scanC_kernel<<<NB, 256, 0, stream>>>(cnt, partials, offsets, N);
    hipMemsetAsync(cnt, 0, (size_t)N * sizeof(int), stream);  // -> cursor
    bucket_kernel<<<(E + 255) / 256, 256, 0, stream>>>(ei, offsets, cnt, csr_row, E);

    if (ws_size >= need_full) {
      cvt_w_kernel<<<64, 256, 0, stream>>>(W, Wt);
      gemm_mfma_kernel<<<(N + 63) / 64, 256, 0, stream>>>(x, Wt, dis, hb, N);
      int nagg = min(AGG_BLOCKS, (N + 15) / 16);
      if (ws_size >= need_agb) {
        csr_agg_stats_bf16_kernel<<<nagg, 256, 0, stream>>>(
            csr_row, offsets, dis, (const uint4*)hb, (uint4*)agb, sums, N, E);
        final_fused_kernel<<<2048, 256, 0, stream>>>(
            x, (const uint4*)agb, sums, gamma, beta, out, N);
      } else {
        csr_agg_stats_kernel<<<nagg, 256, 0, stream>>>(
            csr_row, offsets, dis, (const uint4*)hb, out, sums, N, E);
        bn_finalize_kernel<<<1, 128, 0, stream>>>(sums, mv, N);
        final4_kernel<<<(N * 32 + 255) / 256, 256, 0, stream>>>(
            x, mv, gamma, beta, out, N * 32);
      }
    } else {
      csr_agg_kernel<<<(N + 3) / 4, 256, 0, stream>>>(csr_row, offsets, dis, x, out, N, E);
      gemm_stats_kernel<<<GEMM_GRID, 256, 0, stream>>>(W, out, sums, N);
      bn_finalize_kernel<<<1, 128, 0, stream>>>(sums, mv, N);
      final4_kernel<<<(N * 32 + 255) / 256, 256, 0, stream>>>(
          x, mv, gamma, beta, out, N * 32);
    }
  } else {
    // ---- fallback: proven atomic-scatter path ----
    float* deg  = (float*)ws;
    float* sums = deg + N;
    float* mv   = sums + 2 * D;
    hipMemsetAsync(deg, 0, (size_t)N * sizeof(float), stream);
    hipMemsetAsync(sums, 0, 2 * D * sizeof(float), stream);
    hipMemsetAsync(out, 0, (size_t)out_size * sizeof(float), stream);
    degree_f_kernel<<<(E + 255) / 256, 256, 0, stream>>>(ei + E, deg, E);
    dis_kernel<<<(N + 255) / 256, 256, 0, stream>>>(deg, N);
    scatter_kernel<<<(E + 1) / 2, 256, 0, stream>>>(ei, x, deg, out, E);
    gemm_stats_kernel<<<GEMM_GRID, 256, 0, stream>>>(W, out, sums, N);
    bn_finalize_kernel<<<1, 128, 0, stream>>>(sums, mv, N);
    final4_kernel<<<(N * 32 + 255) / 256, 256, 0, stream>>>(x, mv, gamma, beta, out, N * 32);
  }
}